// Round 4
// baseline (477.300 us; speedup 1.0000x reference)
//
#include <hip/hip_runtime.h>

typedef __attribute__((ext_vector_type(8))) short short8;
typedef __attribute__((ext_vector_type(4))) float floatx4;

static __device__ __forceinline__ unsigned short f2bf(float x) {
    unsigned int u = __float_as_uint(x);
    u += 0x7fffu + ((u >> 16) & 1u);
    return (unsigned short)(u >> 16);
}
static __device__ __forceinline__ float bf2f(unsigned short h) {
    return __uint_as_float(((unsigned int)h) << 16);
}

// ---------------- K1: histogram of iid ----------------
__global__ void k_hist(const int* __restrict__ iid, int* __restrict__ counts, int N) {
    int n = blockIdx.x * blockDim.x + threadIdx.x;
    if (n < N) atomicAdd(&counts[iid[n]], 1);
}

// ---------------- K2: fp32->bf16 convert + count-weighted stats (one feat pass) ------
__global__ __launch_bounds__(256) void k_cvtstats(const float* __restrict__ feat,
                                                  const int* __restrict__ counts,
                                                  unsigned short* __restrict__ featb,
                                                  float* __restrict__ dsum, float* __restrict__ dsumsq,
                                                  int V) {
    int tid = threadIdx.x;
    int r2 = tid >> 7, d = tid & 127;
    float s = 0.f, qa = 0.f;
    for (int vp = blockIdx.x; vp * 2 < V; vp += gridDim.x) {
        int v = vp * 2 + r2;
        if (v >= V) continue;
        float f = feat[(size_t)v * 128 + d];
        featb[(size_t)v * 128 + d] = f2bf(f);
        float c = (float)counts[v];
        if (c != 0.f) { s += c * f; qa += c * f * f; }
    }
    __shared__ float red[256];
    red[tid] = s; __syncthreads();
    if (tid < 128) atomicAdd(&dsum[d], red[tid] + red[tid + 128]);
    __syncthreads();
    red[tid] = qa; __syncthreads();
    if (tid < 128) atomicAdd(&dsumsq[d], red[tid] + red[tid + 128]);
}

// ---------------- K3: BN affine constants ----------------
__global__ __launch_bounds__(128) void k_affine(const float* __restrict__ sum,
                                                const float* __restrict__ sumsq,
                                                const float* __restrict__ gamma,
                                                const float* __restrict__ beta,
                                                float* __restrict__ scale, float* __restrict__ shift,
                                                float invN) {
    int d = threadIdx.x;
    float mean = sum[d] * invN;
    float var  = sumsq[d] * invN - mean * mean;
    float sc   = gamma[d] * rsqrtf(var + 1e-5f);
    scale[d] = sc;
    shift[d] = beta[d] - mean * sc;
}

// ---------------- K4: fold scale into weights; fused bias ----------------
__global__ __launch_bounds__(128) void k_prep(const float* __restrict__ Wu, const float* __restrict__ Wv,
                                              const float* __restrict__ bv,
                                              const float* __restrict__ scale, const float* __restrict__ shift,
                                              unsigned short* __restrict__ wut, float* __restrict__ wvs,
                                              float* __restrict__ cbias) {
    int h = blockIdx.x, d = threadIdx.x;
    float sc = scale[d], sh = shift[d];
    float wu = Wu[d * 128 + h], wv = Wv[d * 128 + h];
    wut[h * 128 + d] = f2bf(sc * wu);
    wvs[d * 128 + h] = sc * wv;
    __shared__ float red[128];
    red[d] = sh * (wu + wv);
    __syncthreads();
    for (int off = 64; off > 0; off >>= 1) {
        if (d < off) red[d] += red[d + off];
        __syncthreads();
    }
    if (d == 0) cbias[h] = bv[h] + red[0];
}

// ---------------- K5: feat_v per graph (32 graphs/block to amortize wvs) ----------------
__global__ __launch_bounds__(256) void k_fv(const float* __restrict__ feat, const int* __restrict__ iid,
                                            const int* __restrict__ last, const float* __restrict__ wvs,
                                            const float* __restrict__ cbias, float* __restrict__ fv,
                                            int B) {
    const int GPB = 32;
    int b0 = blockIdx.x * GPB;
    int tid = threadIdx.x;
    int h = tid & 127, half = tid >> 7;   // half in {0,1}
    __shared__ float sx[GPB][128];
    for (int g = half; g < GPB; g += 2) {
        int b = b0 + g;
        int row = (b < B) ? iid[last[b]] : 0;
        sx[g][h] = feat[(size_t)row * 128 + h];
    }
    __syncthreads();
    float acc[16];
#pragma unroll
    for (int g = 0; g < 16; ++g) acc[g] = 0.f;
    for (int d = 0; d < 128; ++d) {
        float w = wvs[d * 128 + h];        // coalesced; broadcast across halves
#pragma unroll
        for (int g = 0; g < 16; ++g) acc[g] += sx[half * 16 + g][d] * w;
    }
    float cb = cbias[h];
    for (int g = 0; g < 16; ++g) {
        int b = b0 + half * 16 + g;
        if (b < B) fv[(size_t)b * 128 + h] = acc[g] + cb;
    }
}

// ---------------- K6: fully fused main ----------------
// Per 64-node tile T (3-buffer rotation, 2 barriers/iter):
//   B1 -> stage(T+1, DMA)  |  phaseX: ex=exp(e[T-1]), denom atomics (1/seg)
//   MFMA+epilogue(T) -> e partials    B2 -> scan: rstu[seg] += ex * rows(T-1) from LDS
__global__ __launch_bounds__(256, 3) void k_main(
        const unsigned short* __restrict__ featb, const int* __restrict__ iid,
        const int* __restrict__ seg, const unsigned short* __restrict__ wut,
        const float* __restrict__ fv, const float* __restrict__ we_g,
        float* __restrict__ denom, float* __restrict__ rstu,
        int N, int numTiles) {
    __shared__ unsigned short sA[3][64 * 128];   // 48 KB, XOR-swizzled 16B chunks
    __shared__ int   sSeg[3][64];
    __shared__ float sEp[2][4][64];
    __shared__ float sEx[64];

    int tid = threadIdx.x;
    int wv = tid >> 6, lane = tid & 63, q = lane >> 4, c = lane & 15;
    int p2 = lane & 15;
    int rowbase = wv * 16 + (lane >> 4);

    // one-time B fragments in registers (2 h-tiles per wave)
    short8 bfr[2][4];
    float we2[2];
#pragma unroll
    for (int t = 0; t < 2; ++t) {
        int h = (2 * wv + t) * 16 + c;
        we2[t] = we_g[h];
#pragma unroll
        for (int kc = 0; kc < 4; ++kc)
            bfr[t][kc] = *(const short8*)(wut + h * 128 + kc * 32 + q * 8);
    }

    if (blockIdx.x >= numTiles) return;

    int iidR[4]; int segR;
    auto loadRegs = [&](int T) {
        int n0 = T << 6;
#pragma unroll
        for (int k = 0; k < 4; ++k)
            iidR[k] = iid[min(n0 + rowbase + 4 * k, N - 1)];
        segR = seg[min(n0 + (tid & 63), N - 1)];
    };
    auto stage = [&](int buf) {
        unsigned short* sAb = &sA[buf][0];
#pragma unroll
        for (int k = 0; k < 4; ++k) {
            int row = rowbase + 4 * k;
            int j = (p2 & 8) | ((p2 & 7) ^ (row & 7));
            const unsigned short* g = featb + (size_t)iidR[k] * 128 + j * 8;
            __builtin_amdgcn_global_load_lds(
                (const __attribute__((address_space(1))) void*)g,
                (__attribute__((address_space(3))) void*)(sAb + wv * 2048 + k * 512),
                16, 0, 0);
        }
        if (tid < 64) sSeg[buf][tid] = segR;
    };

    // phaseX: finalize e for tile Tp, write sEx, per-segment denom atomic (wave 0 only)
    auto phaseX = [&](int bufP, int Tp, int epb) {
        if (tid < 64) {
            float s = sEp[epb][0][tid] + sEp[epb][1][tid]
                    + sEp[epb][2][tid] + sEp[epb][3][tid];
            int n = (Tp << 6) + tid;
            int sg2 = sSeg[bufP][tid];
            float ex = (n < N) ? __expf(s) : 0.f;
            sEx[tid] = ex;
            // segmented suffix-sum over the 64 sorted lanes -> one atomic per segment
            float v = ex;
#pragma unroll
            for (int off = 1; off < 64; off <<= 1) {
                float o = __shfl_down(v, off);
                int so = __shfl_down(sg2, off);
                if (tid + off < 64 && so == sg2) v += o;
            }
            bool head = (tid == 0) || (sSeg[bufP][tid - 1] != sg2);
            if (head) atomicAdd(&denom[sg2], v);
        }
    };

    // scan: rstu[seg][d] += ex * row[d] for tile in bufP (rows still in LDS)
    int sd = tid & 127, sgrp = tid >> 7;
    int cch = sd >> 3;
    int sbase = (cch & 8) * 8 + (sd & 7);
    int c7 = cch & 7;
    auto scanTile = [&](int bufP) {
        float a = 0.f;
        int j0 = sgrp * 32;
        const unsigned short* bp = &sA[bufP][0];
        int cur = sSeg[bufP][j0];
#pragma unroll 4
        for (int j = j0; j < j0 + 32; ++j) {
            int s2 = sSeg[bufP][j];
            if (s2 != cur) {                   // group-uniform branch
                atomicAdd(&rstu[((size_t)cur << 7) + sd], a);
                a = 0.f; cur = s2;
            }
            int addr = j * 128 + sbase + ((c7 ^ (j & 7)) << 3);
            a += sEx[j] * bf2f(bp[addr]);
        }
        atomicAdd(&rstu[((size_t)cur << 7) + sd], a);
    };

    int G = gridDim.x;
    int T = blockIdx.x;
    loadRegs(T);
    stage(0);
    int prevT = -1;
    int it = 0;
    int h0 = wv * 32 + c;

    while (true) {
        int bufC = it % 3;
        int Tn = T + G;
        bool hn = (Tn < numTiles);
        if (hn) loadRegs(Tn);
        __syncthreads();                 // B1: stage(T) complete; sEp(T-1) sealed; prev scan readers done
        if (hn) stage((it + 1) % 3);
        int bufP = (it + 2) % 3;
        if (prevT >= 0) phaseX(bufP, prevT, (it ^ 1) & 1);

        // ---- MFMA tile T from bufC ----
        floatx4 acc[4][2];
#pragma unroll
        for (int mt = 0; mt < 4; ++mt)
#pragma unroll
            for (int t = 0; t < 2; ++t) acc[mt][t] = (floatx4)(0.f);
#pragma unroll
        for (int kc = 0; kc < 4; ++kc) {
            int jj = 4 * kc + q;
            int pofs = ((jj & 8) | ((jj & 7) ^ (c & 7))) * 8;
            short8 a0 = *(const short8*)&sA[bufC][( 0 + c) * 128 + pofs];
            short8 a1 = *(const short8*)&sA[bufC][(16 + c) * 128 + pofs];
            short8 a2 = *(const short8*)&sA[bufC][(32 + c) * 128 + pofs];
            short8 a3 = *(const short8*)&sA[bufC][(48 + c) * 128 + pofs];
#pragma unroll
            for (int t = 0; t < 2; ++t) {
                acc[0][t] = __builtin_amdgcn_mfma_f32_16x16x32_bf16(a0, bfr[t][kc], acc[0][t], 0, 0, 0);
                acc[1][t] = __builtin_amdgcn_mfma_f32_16x16x32_bf16(a1, bfr[t][kc], acc[1][t], 0, 0, 0);
                acc[2][t] = __builtin_amdgcn_mfma_f32_16x16x32_bf16(a2, bfr[t][kc], acc[2][t], 0, 0, 0);
                acc[3][t] = __builtin_amdgcn_mfma_f32_16x16x32_bf16(a3, bfr[t][kc], acc[3][t], 0, 0, 0);
            }
        }
        // ---- epilogue: partial e over this wave's 32 h-columns (fv via L1) ----
#pragma unroll
        for (int mt = 0; mt < 4; ++mt)
#pragma unroll
            for (int r = 0; r < 4; ++r) {
                int nl = mt * 16 + q * 4 + r;
                int sg2 = sSeg[bufC][nl];
                const float* fvp = fv + ((size_t)sg2 << 7);
                float u0 = acc[mt][0][r] + fvp[h0];
                float u1 = acc[mt][1][r] + fvp[h0 + 16];
                float p = we2[0] * __builtin_amdgcn_rcpf(1.f + __expf(-u0))
                        + we2[1] * __builtin_amdgcn_rcpf(1.f + __expf(-u1));
                p += __shfl_xor(p, 1);
                p += __shfl_xor(p, 2);
                p += __shfl_xor(p, 4);
                p += __shfl_xor(p, 8);
                if (c == 0) sEp[it & 1][wv][nl] = p;
            }

        __syncthreads();                 // B2: sEx ready; stage(T+1) drained; sEp irrelevant here
        if (prevT >= 0) scanTile(bufP);
        prevT = T;
        if (!hn) break;
        T = Tn; ++it;
    }
    // cleanup: finalize last tile
    __syncthreads();
    phaseX(it % 3, prevT, it & 1);
    __syncthreads();
    scanTile(it % 3);
}

// ---------------- K7: out = (scale*rstu/denom + shift*(denom>0)) @ W_out ----------------
__global__ __launch_bounds__(256) void k_out(const float* __restrict__ rstu, const float* __restrict__ denomA,
                                             const float* __restrict__ scale, const float* __restrict__ shift,
                                             const float* __restrict__ Wout, float* __restrict__ out, int B) {
    __shared__ float sT[128][36];
    int b0 = blockIdx.x * 32;
    int t = threadIdx.x;
    for (int i = 0; i < 16; ++i) {
        int idx = i * 256 + t;
        int r = idx >> 7, d = idx & 127;
        int b = min(b0 + r, B - 1);
        float dn = denomA[b];
        float inv = (dn > 0.f) ? 1.f / dn : 0.f;
        float msk = (dn > 0.f) ? 1.f : 0.f;
        sT[d][r] = rstu[((size_t)b << 7) + d] * scale[d] * inv + shift[d] * msk;
    }
    __syncthreads();
    float acc[32];
#pragma unroll
    for (int r = 0; r < 32; ++r) acc[r] = 0.f;
    for (int dd = 0; dd < 128; ++dd) {
        float w = Wout[dd * 256 + t];
        const float4* row = (const float4*)&sT[dd][0];
#pragma unroll
        for (int r4 = 0; r4 < 8; ++r4) {
            float4 v = row[r4];
            acc[r4 * 4 + 0] += w * v.x;
            acc[r4 * 4 + 1] += w * v.y;
            acc[r4 * 4 + 2] += w * v.z;
            acc[r4 * 4 + 3] += w * v.w;
        }
    }
    for (int r = 0; r < 32; ++r)
        if (b0 + r < B) out[(size_t)(b0 + r) * 256 + t] = acc[r];
}

extern "C" void kernel_launch(void* const* d_in, const int* in_sizes, int n_in,
                              void* d_out, int out_size, void* d_ws, size_t ws_size,
                              hipStream_t stream) {
    const float* feat  = (const float*)d_in[0];
    const int*   iid   = (const int*)d_in[1];
    const int*   seg   = (const int*)d_in[2];
    const int*   last  = (const int*)d_in[3];
    const float* gamma = (const float*)d_in[4];
    const float* beta  = (const float*)d_in[5];
    const float* Wu    = (const float*)d_in[6];
    const float* Wv    = (const float*)d_in[7];
    const float* bv    = (const float*)d_in[8];
    const float* we    = (const float*)d_in[9];
    const float* Wout  = (const float*)d_in[10];
    float* out = (float*)d_out;

    int V = in_sizes[0] / 128;
    int N = in_sizes[1];
    int B = in_sizes[3];

    char* w = (char*)d_ws;
    size_t off = 0;
    auto alloc = [&](size_t bytes) -> void* {
        void* p = w + off;
        off += (bytes + 255) & ~(size_t)255;
        return p;
    };
    // zero-init region
    int*   counts = (int*)alloc((size_t)V * 4);
    float* dsum   = (float*)alloc(512);
    float* dsumsq = (float*)alloc(512);
    float* denom  = (float*)alloc((size_t)B * 4);
    float* rstu   = (float*)alloc((size_t)B * 128 * 4);
    size_t zero_bytes = off;
    // rest
    float* scale  = (float*)alloc(512);
    float* shift  = (float*)alloc(512);
    float* cbias  = (float*)alloc(512);
    unsigned short* wut = (unsigned short*)alloc(128 * 128 * 2);
    float* wvs    = (float*)alloc(128 * 128 * 4);
    float* fv     = (float*)alloc((size_t)B * 128 * 4);
    unsigned short* featb = (unsigned short*)alloc((size_t)V * 128 * 2);
    (void)ws_size; (void)n_in; (void)out_size;

    hipMemsetAsync(d_ws, 0, zero_bytes, stream);

    k_hist<<<(N + 255) / 256, 256, 0, stream>>>(iid, counts, N);
    k_cvtstats<<<1024, 256, 0, stream>>>(feat, counts, featb, dsum, dsumsq, V);
    k_affine<<<1, 128, 0, stream>>>(dsum, dsumsq, gamma, beta, scale, shift, 1.0f / (float)N);
    k_prep<<<128, 128, 0, stream>>>(Wu, Wv, bv, scale, shift, wut, wvs, cbias);
    k_fv<<<(B + 31) / 32, 256, 0, stream>>>(feat, iid, last, wvs, cbias, fv, B);

    int numTiles = (N + 63) / 64;
    k_main<<<768, 256, 0, stream>>>(featb, iid, seg, wut, fv, we, denom, rstu, N, numTiles);

    k_out<<<(B + 31) / 32, 256, 0, stream>>>(rstu, denom, scale, shift, Wout, out, B);
}